// Round 1
// baseline (9510.990 us; speedup 1.0000x reference)
//
#include <hip/hip_runtime.h>
#include <hip/hip_bf16.h>
#include <cstdint>
#include <cstddef>

#define Bsz 64
#define Tn  512
#define Dn  512
#define Hn  512
#define NG  2048        // 4*H
#define GWG 32          // workgroups per direction
#define NCOL 16         // h-columns per WG

typedef __attribute__((ext_vector_type(8))) short short8;
typedef __attribute__((ext_vector_type(4))) float f32x4;

__device__ __forceinline__ unsigned short f2bf(float f) {
  union { float f; uint32_t u; } v; v.f = f;
  uint32_t u = v.u;
  uint32_t r = (u + 0x7fffu + ((u >> 16) & 1u)) >> 16;
  return (unsigned short)r;
}

__device__ __forceinline__ float sigm(float x) { return 1.0f / (1.0f + __expf(-x)); }
// overflow-safe tanh: x->+inf => 1, x->-inf => -1
__device__ __forceinline__ float tanh_f(float x) { return 1.0f - 2.0f / (__expf(2.0f * x) + 1.0f); }

// ---------------- prep kernel 1: cast x fp32 -> bf16 ----------------
__global__ __launch_bounds__(256) void cast_x_kernel(const float* __restrict__ x,
                                                     unsigned short* __restrict__ xb) {
  size_t i = ((size_t)blockIdx.x * 256 + threadIdx.x) * 8;
  f32x4 a = *(const f32x4*)(x + i);
  f32x4 b = *(const f32x4*)(x + i + 4);
  short8 r;
  r[0] = (short)f2bf(a[0]); r[1] = (short)f2bf(a[1]);
  r[2] = (short)f2bf(a[2]); r[3] = (short)f2bf(a[3]);
  r[4] = (short)f2bf(b[0]); r[5] = (short)f2bf(b[1]);
  r[6] = (short)f2bf(b[2]); r[7] = (short)f2bf(b[3]);
  *(short8*)(xb + i) = r;
}

// ---------------- prep kernel 2: swizzle weights into MFMA B-fragment order ----------------
// frag layout (bf16 elements): [dir(2)][wg(32)][nt(4)][kc(16)][lane(64)][j(8)]
//   n = nt*512 + wg*16 + (lane&15)   (z-column; nt == gate index)
//   k = kc*32 + (lane>>4)*8 + j      (contraction index within the 512-row weight matrix)
__global__ __launch_bounds__(256) void swizzle_w_kernel(
    const float* __restrict__ Wfk, const float* __restrict__ Wfr,
    const float* __restrict__ Wbk, const float* __restrict__ Wbr,
    unsigned short* __restrict__ wkf, unsigned short* __restrict__ wrf)
{
  int idx = blockIdx.x * 256 + threadIdx.x;   // 0 .. 262143
  int arr  = blockIdx.y;                       // 0 = Wk (input proj), 1 = Wr (recurrent)
  int lane = idx & 63;
  int kc   = (idx >> 6) & 15;
  int nt   = (idx >> 10) & 3;
  int wg   = (idx >> 12) & 31;
  int dir  = (idx >> 17) & 1;
  const float* W = arr ? (dir ? Wbr : Wfr) : (dir ? Wbk : Wfk);
  unsigned short* dst = (arr ? wrf : wkf) + (size_t)idx * 8;
  int n  = nt * 512 + wg * NCOL + (lane & 15);
  int k0 = kc * 32 + ((lane >> 4) & 3) * 8;
#pragma unroll
  for (int j = 0; j < 8; ++j) dst[j] = f2bf(W[(size_t)(k0 + j) * NG + n]);
}

// ---------------- main persistent LSTM kernel ----------------
__global__ __launch_bounds__(256) void lstm_main_kernel(
    const unsigned short* __restrict__ xb,   // [B][T][D] bf16
    const unsigned short* __restrict__ wkf,  // Wk frags
    const unsigned short* __restrict__ wrf,  // Wr frags
    const float* __restrict__ bias_f, const float* __restrict__ bias_b,
    unsigned short* __restrict__ hbuf,       // [2 dir][2 phase][B][H] bf16
    int* __restrict__ flags,                 // [2 dir][T]
    float* __restrict__ out)                 // word_emb [B][T][2H] ++ sent_emb [B][2H]
{
  const int wg   = blockIdx.x;     // 0..31  (h-column slice)
  const int dir  = blockIdx.y;     // 0 fwd, 1 bwd
  const int tid  = threadIdx.x;
  const int lane = tid & 63;
  const int wv   = tid >> 6;       // wave id = m-tile (16 batch rows)
  const int quad = lane >> 4;
  const int col  = lane & 15;

  __shared__ short8 wr_lds[4 * 16 * 64];     // 64 KB: Wr fragments, resident all 512 steps

  // stage Wr frags into LDS (fully coalesced 16B/lane)
  {
    const short8* src = (const short8*)wrf + (size_t)(dir * GWG + wg) * 4096;
    for (int i = tid; i < 4096; i += 256) wr_lds[i] = src[i];
  }
  const short8* wk = (const short8*)wkf + (size_t)(dir * GWG + wg) * 4096;

  const float* bias = dir ? bias_b : bias_f;
  float bz[4];
#pragma unroll
  for (int g = 0; g < 4; ++g) bz[g] = bias[g * 512 + wg * NCOL + col];

  float cst[4] = {0.f, 0.f, 0.f, 0.f};       // c-state, fp32, lives in VGPRs all steps

  const int am = wv * 16 + col;              // batch row for A-fragment loads
  unsigned short* hb0 = hbuf + (size_t)dir * 2 * Bsz * Hn;   // phase 0
  unsigned short* hb1 = hb0 + (size_t)Bsz * Hn;              // phase 1
  int* flg = flags + dir * Tn;

  __syncthreads();

  for (int t = 0; t < Tn; ++t) {
    const int tx = dir ? (Tn - 1 - t) : t;   // original time index
    f32x4 a0 = {0.f,0.f,0.f,0.f}, a1 = {0.f,0.f,0.f,0.f};
    f32x4 a2 = {0.f,0.f,0.f,0.f}, a3 = {0.f,0.f,0.f,0.f};

    // ---- x-half: z += x_t @ Wk   (independent of h -> runs while producers finish) ----
    const short8* xrow = (const short8*)(xb + ((size_t)am * Tn + tx) * Dn);
#pragma unroll 4
    for (int kc = 0; kc < 16; ++kc) {
      short8 a = xrow[kc * 4 + quad];
      a0 = __builtin_amdgcn_mfma_f32_16x16x32_bf16(a, wk[(0*16+kc)*64 + lane], a0, 0,0,0);
      a1 = __builtin_amdgcn_mfma_f32_16x16x32_bf16(a, wk[(1*16+kc)*64 + lane], a1, 0,0,0);
      a2 = __builtin_amdgcn_mfma_f32_16x16x32_bf16(a, wk[(2*16+kc)*64 + lane], a2, 0,0,0);
      a3 = __builtin_amdgcn_mfma_f32_16x16x32_bf16(a, wk[(3*16+kc)*64 + lane], a3, 0,0,0);
    }

    // ---- wait for all 32 producers of h_{t-1} ----
    if (t > 0) {
      if (tid == 0) {
        while (__hip_atomic_load(flg + (t - 1), __ATOMIC_ACQUIRE, __HIP_MEMORY_SCOPE_AGENT) < GWG)
          __builtin_amdgcn_s_sleep(1);
      }
      __syncthreads();
    }
    const unsigned short* hprev = (t & 1) ? hb0 : hb1;  // h_{t-1}; t=0 reads zeroed phase-1
    unsigned short*       hcur  = (t & 1) ? hb1 : hb0;

    // ---- h-half: z += h_{t-1} @ Wr  (Wr frags from LDS) ----
    const short8* hrow = (const short8*)(hprev + (size_t)am * Hn);
#pragma unroll 4
    for (int kc = 0; kc < 16; ++kc) {
      short8 a = hrow[kc * 4 + quad];
      a0 = __builtin_amdgcn_mfma_f32_16x16x32_bf16(a, wr_lds[(0*16+kc)*64 + lane], a0, 0,0,0);
      a1 = __builtin_amdgcn_mfma_f32_16x16x32_bf16(a, wr_lds[(1*16+kc)*64 + lane], a1, 0,0,0);
      a2 = __builtin_amdgcn_mfma_f32_16x16x32_bf16(a, wr_lds[(2*16+kc)*64 + lane], a2, 0,0,0);
      a3 = __builtin_amdgcn_mfma_f32_16x16x32_bf16(a, wr_lds[(3*16+kc)*64 + lane], a3, 0,0,0);
    }

    // ---- gates (C-layout: row = quad*4+r, col = lane&15; nt == gate) ----
#pragma unroll
    for (int r = 0; r < 4; ++r) {
      const int b = wv * 16 + quad * 4 + r;  // batch row
      float zi = a0[r] + bz[0];
      float zf = a1[r] + bz[1];
      float zg = a2[r] + bz[2];
      float zo = a3[r] + bz[3];
      float ig = sigm(zi);
      float fg = sigm(zf);
      float gg = tanh_f(zg);
      float og = sigm(zo);
      float c  = fg * cst[r] + ig * gg;
      cst[r] = c;
      float h  = og * tanh_f(c);
      hcur[(size_t)b * Hn + wg * NCOL + col] = f2bf(h);
      out[((size_t)b * Tn + tx) * (2 * Hn) + dir * Hn + wg * NCOL + col] = h;
      if (t == Tn - 1)
        out[(size_t)Bsz * Tn * (2 * Hn) + (size_t)b * (2 * Hn) + dir * Hn + wg * NCOL + col] = h;
    }

    // ---- publish h_t ----
    __threadfence();
    __syncthreads();
    if (tid == 0)
      __hip_atomic_fetch_add(flg + t, 1, __ATOMIC_RELEASE, __HIP_MEMORY_SCOPE_AGENT);
  }
}

// ---------------- launch ----------------
extern "C" void kernel_launch(void* const* d_in, const int* in_sizes, int n_in,
                              void* d_out, int out_size, void* d_ws, size_t ws_size,
                              hipStream_t stream) {
  const float* x   = (const float*)d_in[0];
  const float* Wfk = (const float*)d_in[1];
  const float* Wfr = (const float*)d_in[2];
  const float* bf_ = (const float*)d_in[3];
  const float* Wbk = (const float*)d_in[4];
  const float* Wbr = (const float*)d_in[5];
  const float* bb_ = (const float*)d_in[6];
  float* out = (float*)d_out;

  char* ws = (char*)d_ws;
  // ws layout (bytes):
  //   xb   : 0          .. 33,554,432   (x cast to bf16)
  //   wkf  : 33,554,432 .. +4,194,304   (Wk frags)
  //   wrf  : 37,748,736 .. +4,194,304   (Wr frags)
  //   hbuf : 41,943,040 .. +262,144     (h double buffers, 2 dirs)
  //   flags: 42,205,184 .. +4,096
  unsigned short* xb   = (unsigned short*)(ws);
  unsigned short* wkf  = (unsigned short*)(ws + 33554432);
  unsigned short* wrf  = (unsigned short*)(ws + 37748736);
  unsigned short* hbuf = (unsigned short*)(ws + 41943040);
  int*            flg  = (int*)           (ws + 42205184);

  hipMemsetAsync(hbuf, 0, 262144 + 4096, stream);                     // h0=c0-home=0, flags=0
  cast_x_kernel<<<8192, 256, 0, stream>>>(x, xb);
  swizzle_w_kernel<<<dim3(1024, 2), 256, 0, stream>>>(Wfk, Wfr, Wbk, Wbr, wkf, wrf);
  lstm_main_kernel<<<dim3(GWG, 2), 256, 0, stream>>>(xb, wkf, wrf, bf_, bb_, hbuf, flg, out);
}

// Round 2
// 4917.685 us; speedup vs baseline: 1.9340x; 1.9340x over previous
//
#include <hip/hip_runtime.h>
#include <hip/hip_bf16.h>
#include <cstdint>
#include <cstddef>

#define Bsz 64
#define Tn  512
#define Dn  512
#define Hn  512
#define NG  2048        // 4*H
#define GWG 32          // workgroups per direction
#define NCOL 16         // h-columns per WG

typedef __attribute__((ext_vector_type(8))) short short8;
typedef __attribute__((ext_vector_type(4))) float f32x4;

union FragU { uint32_t u[4]; short8 s; };

__device__ __forceinline__ unsigned short f2bf(float f) {
  union { float f; uint32_t u; } v; v.f = f;
  uint32_t u = v.u;
  uint32_t r = (u + 0x7fffu + ((u >> 16) & 1u)) >> 16;
  return (unsigned short)r;
}

__device__ __forceinline__ float sigm(float x) { return 1.0f / (1.0f + __expf(-x)); }
__device__ __forceinline__ float tanh_f(float x) { return 1.0f - 2.0f / (__expf(2.0f * x) + 1.0f); }

// ---------------- prep kernel 1: cast x fp32 -> bf16 ----------------
__global__ __launch_bounds__(256) void cast_x_kernel(const float* __restrict__ x,
                                                     unsigned short* __restrict__ xb) {
  size_t i = ((size_t)blockIdx.x * 256 + threadIdx.x) * 8;
  f32x4 a = *(const f32x4*)(x + i);
  f32x4 b = *(const f32x4*)(x + i + 4);
  short8 r;
  r[0] = (short)f2bf(a[0]); r[1] = (short)f2bf(a[1]);
  r[2] = (short)f2bf(a[2]); r[3] = (short)f2bf(a[3]);
  r[4] = (short)f2bf(b[0]); r[5] = (short)f2bf(b[1]);
  r[6] = (short)f2bf(b[2]); r[7] = (short)f2bf(b[3]);
  *(short8*)(xb + i) = r;
}

// ---------------- prep kernel 2: swizzle weights into MFMA B-fragment order ----------------
// frag layout (bf16): [dir(2)][wg(32)][nt(4)][kc(16)][lane(64)][j(8)]
//   n = nt*512 + wg*16 + (lane&15);  k = kc*32 + (lane>>4)*8 + j
__global__ __launch_bounds__(256) void swizzle_w_kernel(
    const float* __restrict__ Wfk, const float* __restrict__ Wfr,
    const float* __restrict__ Wbk, const float* __restrict__ Wbr,
    unsigned short* __restrict__ wkf, unsigned short* __restrict__ wrf)
{
  int idx = blockIdx.x * 256 + threadIdx.x;   // 0 .. 262143
  int arr  = blockIdx.y;                       // 0 = Wk, 1 = Wr
  int lane = idx & 63;
  int kc   = (idx >> 6) & 15;
  int nt   = (idx >> 10) & 3;
  int wg   = (idx >> 12) & 31;
  int dir  = (idx >> 17) & 1;
  const float* W = arr ? (dir ? Wbr : Wfr) : (dir ? Wbk : Wfk);
  unsigned short* dst = (arr ? wrf : wkf) + (size_t)idx * 8;
  int n  = nt * 512 + wg * NCOL + (lane & 15);
  int k0 = kc * 32 + ((lane >> 4) & 3) * 8;
#pragma unroll
  for (int j = 0; j < 8; ++j) dst[j] = f2bf(W[(size_t)(k0 + j) * NG + n]);
}

// ---------------- main persistent LSTM kernel ----------------
// h is exchanged in MFMA A-fragment layout, double-buffered:
//   hfrag[dir(2)][phase(2)][mt(4)][kc(16)][lane(64)][j(8)]  bf16
// flags[dir(2)][t(512)][wv(4)][wg(32)] int — per-producer-WAVE slots.
__global__ __launch_bounds__(256, 1) void lstm_main_kernel(
    const unsigned short* __restrict__ xb,
    const unsigned short* __restrict__ wkf,
    const unsigned short* __restrict__ wrf,
    const float* __restrict__ bias_f, const float* __restrict__ bias_b,
    unsigned short* __restrict__ hbuf,
    int* __restrict__ flags,
    float* __restrict__ out)
{
  const int wg   = blockIdx.x;     // 0..31 (h-column slice)
  const int dir  = blockIdx.y;     // 0 fwd, 1 bwd
  const int tid  = threadIdx.x;
  const int lane = tid & 63;
  const int wv   = tid >> 6;       // wave id = m-tile (16 batch rows)
  const int quad = lane >> 4;
  const int col  = lane & 15;

  __shared__ short8 wr_lds[4 * 16 * 64];     // 64 KB Wr fragments

  {
    const short8* src = (const short8*)wrf + (size_t)(dir * GWG + wg) * 4096;
    for (int i = tid; i < 4096; i += 256) wr_lds[i] = src[i];
  }
  const short8* wk = (const short8*)wkf + (size_t)(dir * GWG + wg) * 4096;

  const float* bias = dir ? bias_b : bias_f;
  float bz[4];
#pragma unroll
  for (int g = 0; g < 4; ++g) bz[g] = bias[g * 512 + wg * NCOL + col];

  float cst[4] = {0.f, 0.f, 0.f, 0.f};

  const int am = wv * 16 + col;              // batch row for A-fragment loads
  unsigned short* hf_base = hbuf + (size_t)dir * 65536;   // 2 phases x 32768 shorts
  int* flgbase = flags + dir * Tn * 4 * GWG;

  // producer h-store constants (fragment-layout address for this lane's column pair)
  const int kcW = wg >> 1;
  const int c0  = col & ~1;
  const int qd2 = (((wg & 1) << 4) + c0) >> 3;   // k-quad of this column pair
  const int j2  = c0 & 7;
  const int r0  = (col & 1) << 1;                 // even lane stores r=0,1; odd r=2,3
  // uint offset for r: (((wv*16+kcW)*64 + qd2*16 + quad*4 + r)*8 + j2) / 2
  const int eBase = (((wv * 16 + kcW) * 64 + qd2 * 16 + quad * 4 + r0) * 8 + j2) >> 1;

  __syncthreads();   // wr_lds ready (only barrier outside the t-loop)

  for (int t = 0; t < Tn; ++t) {
    const int tx = dir ? (Tn - 1 - t) : t;
    f32x4 a0 = {0.f,0.f,0.f,0.f}, a1 = {0.f,0.f,0.f,0.f};
    f32x4 a2 = {0.f,0.f,0.f,0.f}, a3 = {0.f,0.f,0.f,0.f};

    // ---- x-half (independent of h; overlaps producer latency) ----
    const short8* xrow = (const short8*)(xb + ((size_t)am * Tn + tx) * Dn);
#pragma unroll 4
    for (int kc = 0; kc < 16; ++kc) {
      short8 a = xrow[kc * 4 + quad];
      a0 = __builtin_amdgcn_mfma_f32_16x16x32_bf16(a, wk[(0*16+kc)*64 + lane], a0, 0,0,0);
      a1 = __builtin_amdgcn_mfma_f32_16x16x32_bf16(a, wk[(1*16+kc)*64 + lane], a1, 0,0,0);
      a2 = __builtin_amdgcn_mfma_f32_16x16x32_bf16(a, wk[(2*16+kc)*64 + lane], a2, 0,0,0);
      a3 = __builtin_amdgcn_mfma_f32_16x16x32_bf16(a, wk[(3*16+kc)*64 + lane], a3, 0,0,0);
    }

    // ---- per-wave poll: all 32 producer waves of my m-tile published t-1 ----
    if (t > 0) {
      const int* fl = flgbase + ((t - 1) * 4 + wv) * GWG;
      for (;;) {
        int v = __hip_atomic_load(fl + (lane & 31), __ATOMIC_RELAXED, __HIP_MEMORY_SCOPE_AGENT);
        if (__ballot(v != 0) == ~0ull) break;
        __builtin_amdgcn_s_sleep(1);
      }
    }

    const uint32_t* hp = (const uint32_t*)(hf_base + ((t & 1) ^ 1) * 32768);
    uint32_t*       hc = (uint32_t*)(hf_base + (t & 1) * 32768);

    // ---- load all h A-fragments (relaxed sc1 dwords, all in flight) ----
    FragU hfr[16];
#pragma unroll
    for (int kc = 0; kc < 16; ++kc) {
      const uint32_t* p = hp + ((size_t)(wv * 16 + kc) * 64 + lane) * 4;
#pragma unroll
      for (int d = 0; d < 4; ++d)
        hfr[kc].u[d] = __hip_atomic_load(p + d, __ATOMIC_RELAXED, __HIP_MEMORY_SCOPE_AGENT);
    }

    // ---- h-half MFMAs (Wr from LDS) ----
#pragma unroll
    for (int kc = 0; kc < 16; ++kc) {
      short8 a = hfr[kc].s;
      a0 = __builtin_amdgcn_mfma_f32_16x16x32_bf16(a, wr_lds[(0*16+kc)*64 + lane], a0, 0,0,0);
      a1 = __builtin_amdgcn_mfma_f32_16x16x32_bf16(a, wr_lds[(1*16+kc)*64 + lane], a1, 0,0,0);
      a2 = __builtin_amdgcn_mfma_f32_16x16x32_bf16(a, wr_lds[(2*16+kc)*64 + lane], a2, 0,0,0);
      a3 = __builtin_amdgcn_mfma_f32_16x16x32_bf16(a, wr_lds[(3*16+kc)*64 + lane], a3, 0,0,0);
    }

    // ---- gates ----
    float hv[4];
#pragma unroll
    for (int r = 0; r < 4; ++r) {
      float zi = a0[r] + bz[0];
      float zf = a1[r] + bz[1];
      float zg = a2[r] + bz[2];
      float zo = a3[r] + bz[3];
      float ig = sigm(zi);
      float fg = sigm(zf);
      float gg = tanh_f(zg);
      float og = sigm(zo);
      float c  = fg * cst[r] + ig * gg;
      cst[r] = c;
      hv[r] = og * tanh_f(c);
    }

    // ---- publish h in fragment layout (pack column pair via one shfl_xor) ----
    unsigned short hb16[4];
#pragma unroll
    for (int r = 0; r < 4; ++r) hb16[r] = f2bf(hv[r]);
    uint32_t msg = (col & 1) ? ((uint32_t)hb16[0] | ((uint32_t)hb16[1] << 16))
                             : ((uint32_t)hb16[2] | ((uint32_t)hb16[3] << 16));
    uint32_t got = (uint32_t)__shfl_xor((int)msg, 1);
    uint32_t pkA, pkB;
    if ((col & 1) == 0) {      // store r=0,1; mine is low (even col)
      pkA = (uint32_t)hb16[0] | ((got & 0xffffu) << 16);
      pkB = (uint32_t)hb16[1] | ((got >> 16) << 16);
    } else {                   // store r=2,3; partner is low
      pkA = (got & 0xffffu) | ((uint32_t)hb16[2] << 16);
      pkB = (got >> 16)     | ((uint32_t)hb16[3] << 16);
    }
    __hip_atomic_store(hc + eBase,     pkA, __ATOMIC_RELAXED, __HIP_MEMORY_SCOPE_AGENT);
    __hip_atomic_store(hc + eBase + 4, pkB, __ATOMIC_RELAXED, __HIP_MEMORY_SCOPE_AGENT);

    // ---- flag publish: drain vmem (covers h stores AND this step's h loads), then flag ----
    __threadfence_block();
    __builtin_amdgcn_s_waitcnt(0);
    if (lane == 0)
      __hip_atomic_store(flgbase + (t * 4 + wv) * GWG + wg, 1,
                         __ATOMIC_RELAXED, __HIP_MEMORY_SCOPE_AGENT);

    // ---- out stores (off critical path, after flag) ----
#pragma unroll
    for (int r = 0; r < 4; ++r) {
      const int b = wv * 16 + quad * 4 + r;
      out[((size_t)b * Tn + tx) * (2 * Hn) + dir * Hn + wg * NCOL + col] = hv[r];
      if (t == Tn - 1)
        out[(size_t)Bsz * Tn * (2 * Hn) + (size_t)b * (2 * Hn) + dir * Hn + wg * NCOL + col] = hv[r];
    }
  }
}

// ---------------- launch ----------------
extern "C" void kernel_launch(void* const* d_in, const int* in_sizes, int n_in,
                              void* d_out, int out_size, void* d_ws, size_t ws_size,
                              hipStream_t stream) {
  const float* x   = (const float*)d_in[0];
  const float* Wfk = (const float*)d_in[1];
  const float* Wfr = (const float*)d_in[2];
  const float* bf_ = (const float*)d_in[3];
  const float* Wbk = (const float*)d_in[4];
  const float* Wbr = (const float*)d_in[5];
  const float* bb_ = (const float*)d_in[6];
  float* out = (float*)d_out;

  char* ws = (char*)d_ws;
  // ws layout:
  //   xb    : 0          .. 33,554,432
  //   wkf   : 33,554,432 .. +4,194,304
  //   wrf   : 37,748,736 .. +4,194,304
  //   hfrag : 41,943,040 .. +262,144    (2 dir x 2 phase x 64 KB, A-frag layout)
  //   flags : 42,205,184 .. +524,288    (2 x 512 x 4 x 32 ints)
  unsigned short* xb   = (unsigned short*)(ws);
  unsigned short* wkf  = (unsigned short*)(ws + 33554432);
  unsigned short* wrf  = (unsigned short*)(ws + 37748736);
  unsigned short* hbuf = (unsigned short*)(ws + 41943040);
  int*            flg  = (int*)           (ws + 42205184);

  hipMemsetAsync(ws + 41943040, 0, 262144 + 524288, stream);   // h phase buffers + all flags
  cast_x_kernel<<<8192, 256, 0, stream>>>(x, xb);
  swizzle_w_kernel<<<dim3(1024, 2), 256, 0, stream>>>(Wfk, Wfr, Wbk, Wbr, wkf, wrf);
  lstm_main_kernel<<<dim3(GWG, 2), 256, 0, stream>>>(xb, wkf, wrf, bf_, bb_, hbuf, flg, out);
}